// Round 2
// baseline (315.700 us; speedup 1.0000x reference)
//
#include <hip/hip_runtime.h>
#include <math.h>

#define NPTS 131072
#define DDIM 64
#define KMIX 64
#define LOG_2PI 1.8378770664093453f

#define TPB   256
#define WPB   4            // waves per block
#define NPW   64           // examples (n) per wave
#define BATCH 16           // n per inner batch (LDS tile width)
#define NBLK  (NPTS / (WPB * NPW))   // 512 blocks

// ---------------------------------------------------------------------------
// Prep: 64 blocks (one per k) x 64 threads (one per d). Fully parallel.
// At[d][k] = -0.5*exp(-lv),  Bt[d][k] = mu*exp(-lv),
// C[k] = sum_d(-0.5*lv - 0.5*mu^2*exp(-lv)) - 0.5*D*log2pi + (lp[k]-LSE(lp))
// ---------------------------------------------------------------------------
__global__ void gmm_prep(const float* __restrict__ mu,
                         const float* __restrict__ lv,
                         const float* __restrict__ lp,
                         float* __restrict__ At,
                         float* __restrict__ Bt,
                         float* __restrict__ C)
{
    const int k = blockIdx.x;   // 0..63
    const int d = threadIdx.x;  // 0..63

    // LSE over logpriors, computed redundantly per block (lanes span K==64)
    float x = lp[d];
    float m = x;
    #pragma unroll
    for (int off = 32; off > 0; off >>= 1)
        m = fmaxf(m, __shfl_xor(m, off, 64));
    float s = expf(x - m);
    #pragma unroll
    for (int off = 32; off > 0; off >>= 1)
        s += __shfl_xor(s, off, 64);
    const float lse_lp = m + logf(s);

    const float l  = lv[k * DDIM + d];
    const float a  = expf(-l);
    const float mv = mu[k * DDIM + d];
    At[d * KMIX + k] = -0.5f * a;
    Bt[d * KMIX + k] = mv * a;

    float c = -0.5f * l - 0.5f * mv * mv * a;
    #pragma unroll
    for (int off = 32; off > 0; off >>= 1)
        c += __shfl_xor(c, off, 64);
    if (d == 0)
        C[k] = c + (lp[k] - lse_lp) - 0.5f * (float)DDIM * LOG_2PI;
}

// ---------------------------------------------------------------------------
// Main: lane = k. Each lane holds A[d],B[d] for its k in 128 VGPRs (loaded
// once per wave, amortized over 64 n). Per (k,d): 2 FMAs, all-register
// operands:  w += x*(x*A + B).  x loads are wave-uniform float4 broadcasts.
// Per 16-n batch: wave-private LDS transpose (64x17, conflict-free) so that
// lane (q=lane>>4, nn=lane&15) holds the 16 k-values {q*16+j} of column nn:
// LSE = 15 VALU max + shfl_xor(16,32), then coalesced 64B-segment stores.
// ---------------------------------------------------------------------------
__global__ __launch_bounds__(TPB, 2)
void gmm_main(const float* __restrict__ xg,
              const float* __restrict__ At,
              const float* __restrict__ Bt,
              const float* __restrict__ Cc,
              float* __restrict__ out)
{
    __shared__ float tile[WPB][KMIX * 17];
    const int lane = threadIdx.x & 63;                                  // = k
    const int wid  = __builtin_amdgcn_readfirstlane(threadIdx.x >> 6);
    float* T = tile[wid];

    // coefficient registers for this lane's k (coalesced across lanes per d)
    float Ar[DDIM], Br[DDIM];
    #pragma unroll
    for (int d = 0; d < DDIM; ++d) {
        Ar[d] = At[d * KMIX + lane];
        Br[d] = Bt[d * KMIX + lane];
    }
    const float Cr = Cc[lane];

    const int q  = lane >> 4;
    const int nn = lane & 15;
    const int wave_n0 = (blockIdx.x * WPB + wid) * NPW;

    #pragma unroll 1
    for (int b = 0; b < NPW / BATCH; ++b) {
        const int nbase = wave_n0 + b * BATCH;

        float acc[BATCH];
        #pragma unroll
        for (int t = 0; t < BATCH; ++t) {
            const float* xr = xg + (size_t)(nbase + t) * DDIM;
            float a0 = 0.0f, a1 = 0.0f;
            #pragma unroll
            for (int dc = 0; dc < DDIM; dc += 4) {
                const float4 xv = *(const float4*)(xr + dc);  // uniform bcast
                a0 = fmaf(xv.x, fmaf(xv.x, Ar[dc + 0], Br[dc + 0]), a0);
                a1 = fmaf(xv.y, fmaf(xv.y, Ar[dc + 1], Br[dc + 1]), a1);
                a0 = fmaf(xv.z, fmaf(xv.z, Ar[dc + 2], Br[dc + 2]), a0);
                a1 = fmaf(xv.w, fmaf(xv.w, Ar[dc + 3], Br[dc + 3]), a1);
            }
            acc[t] = a0 + a1 + Cr;
        }

        // wave-private transpose: T[k][t]
        #pragma unroll
        for (int t = 0; t < BATCH; ++t)
            T[lane * 17 + t] = acc[t];
        __threadfence_block();

        float w[BATCH];
        #pragma unroll
        for (int j = 0; j < BATCH; ++j)
            w[j] = T[(q * 16 + j) * 17 + nn];
        __threadfence_block();   // reads done before next batch overwrites

        // LSE over k for column nn: 16 in-register + 4-way cross-lane
        float m = w[0];
        #pragma unroll
        for (int j = 1; j < BATCH; ++j) m = fmaxf(m, w[j]);
        m = fmaxf(m, __shfl_xor(m, 16, 64));
        m = fmaxf(m, __shfl_xor(m, 32, 64));
        float s = 0.0f;
        #pragma unroll
        for (int j = 0; j < BATCH; ++j) s += __expf(w[j] - m);
        s += __shfl_xor(s, 16, 64);
        s += __shfl_xor(s, 32, 64);
        const float lse = m + __logf(s);

        // coalesced stores: 4 k-rows x 16 consecutive n (64B segments)
        #pragma unroll
        for (int j = 0; j < BATCH; ++j)
            out[(size_t)(q * 16 + j) * NPTS + nbase + nn] = w[j] - lse;
    }
}

extern "C" void kernel_launch(void* const* d_in, const int* in_sizes, int n_in,
                              void* d_out, int out_size, void* d_ws, size_t ws_size,
                              hipStream_t stream) {
    const float* inputs    = (const float*)d_in[0];  // (N, D)
    const float* mu        = (const float*)d_in[1];  // (K, D)
    const float* logvars   = (const float*)d_in[2];  // (K, D)
    const float* logpriors = (const float*)d_in[3];  // (K,)

    float* out = (float*)d_out;                       // (K, N)

    float* At = (float*)d_ws;
    float* Bt = At + DDIM * KMIX;
    float* Cc = Bt + DDIM * KMIX;

    gmm_prep<<<KMIX, DDIM, 0, stream>>>(mu, logvars, logpriors, At, Bt, Cc);
    gmm_main<<<NBLK, TPB, 0, stream>>>(inputs, At, Bt, Cc, out);
}

// Round 3
// 256.228 us; speedup vs baseline: 1.2321x; 1.2321x over previous
//
#include <hip/hip_runtime.h>
#include <math.h>

#define NPTS 131072
#define DDIM 64
#define KMIX 64
#define LOG_2PI 1.8378770664093453f

// ---------------------------------------------------------------------------
// Prep: 64 blocks (k) x 64 threads (d). Coefficients k-major for s_load:
//   A[k][d] = -0.5*exp(-lv),  B[k][d] = mu*exp(-lv)
//   C[k] = sum_d(-0.5*lv - 0.5*mu^2*exp(-lv)) - 0.5*D*log2pi + (lp[k]-LSE(lp))
// ---------------------------------------------------------------------------
__global__ void gmm_prep(const float* __restrict__ mu,
                         const float* __restrict__ lv,
                         const float* __restrict__ lp,
                         float* __restrict__ A,   // [KMIX][DDIM]
                         float* __restrict__ B,   // [KMIX][DDIM]
                         float* __restrict__ C)   // [KMIX]
{
    const int k = blockIdx.x;   // 0..63
    const int d = threadIdx.x;  // 0..63

    // LSE over logpriors (lanes span K==64), computed redundantly per block
    float x = lp[d];
    float m = x;
    #pragma unroll
    for (int off = 32; off > 0; off >>= 1)
        m = fmaxf(m, __shfl_xor(m, off, 64));
    float s = expf(x - m);
    #pragma unroll
    for (int off = 32; off > 0; off >>= 1)
        s += __shfl_xor(s, off, 64);
    const float lse_lp = m + logf(s);

    const float l  = lv[k * DDIM + d];
    const float ev = expf(-l);
    const float mv = mu[k * DDIM + d];
    A[k * DDIM + d] = -0.5f * ev;
    B[k * DDIM + d] = mv * ev;

    float c = -0.5f * l - 0.5f * mv * mv * ev;
    #pragma unroll
    for (int off = 32; off > 0; off >>= 1)
        c += __shfl_xor(c, off, 64);
    if (d == 0)
        C[k] = c + (lp[k] - lse_lp) - 0.5f * (float)DDIM * LOG_2PI;
}

// ---------------------------------------------------------------------------
// Main: one thread per example n. acc[64] in VGPRs (all indices constant after
// unrolling — never runtime-indexed, so it cannot be demoted to scratch).
// Coefficients are wave-uniform -> scalar loads (s_load_dwordx8) on the scalar
// pipe, leaving the VALU free: inner loop is 2 FMAs per (k,d), each with one
// scalar operand. x is read in 8-float chunks (2x float4) per dc iteration.
// LSE over k is thread-local (tree max / 4-way partial exp-sums); stores are
// coalesced (consecutive lanes -> consecutive n per k-row).
// ---------------------------------------------------------------------------
__global__ __launch_bounds__(256, 4)
void gmm_main(const float* __restrict__ xg,
              const float* __restrict__ A,
              const float* __restrict__ B,
              const float* __restrict__ C,
              float* __restrict__ out)
{
    const int n = blockIdx.x * 256 + threadIdx.x;
    const float* __restrict__ xr = xg + (size_t)n * DDIM;

    float acc[KMIX];
    #pragma unroll
    for (int k = 0; k < KMIX; ++k) acc[k] = 0.0f;

    #pragma unroll 1
    for (int dc = 0; dc < DDIM; dc += 8) {
        const float4 xa = *(const float4*)(xr + dc);
        const float4 xb = *(const float4*)(xr + dc + 4);
        const float xv0 = xa.x, xv1 = xa.y, xv2 = xa.z, xv3 = xa.w;
        const float xv4 = xb.x, xv5 = xb.y, xv6 = xb.z, xv7 = xb.w;
        const float q0 = xv0 * xv0, q1 = xv1 * xv1, q2 = xv2 * xv2, q3 = xv3 * xv3;
        const float q4 = xv4 * xv4, q5 = xv5 * xv5, q6 = xv6 * xv6, q7 = xv7 * xv7;

        const float* __restrict__ Ap = A + dc;
        const float* __restrict__ Bp = B + dc;

        #pragma unroll
        for (int k = 0; k < KMIX; ++k) {
            const float* __restrict__ a = Ap + k * DDIM;  // uniform -> s_load
            const float* __restrict__ b = Bp + k * DDIM;  // uniform -> s_load
            float t = acc[k];
            t = fmaf(q0, a[0], t); t = fmaf(xv0, b[0], t);
            t = fmaf(q1, a[1], t); t = fmaf(xv1, b[1], t);
            t = fmaf(q2, a[2], t); t = fmaf(xv2, b[2], t);
            t = fmaf(q3, a[3], t); t = fmaf(xv3, b[3], t);
            t = fmaf(q4, a[4], t); t = fmaf(xv4, b[4], t);
            t = fmaf(q5, a[5], t); t = fmaf(xv5, b[5], t);
            t = fmaf(q6, a[6], t); t = fmaf(xv6, b[6], t);
            t = fmaf(q7, a[7], t); t = fmaf(xv7, b[7], t);
            acc[k] = t;
        }
    }

    // add per-k constant (uniform -> scalar operand)
    #pragma unroll
    for (int k = 0; k < KMIX; ++k) acc[k] += C[k];

    // tree max over k (constant indices only)
    float t32[32];
    #pragma unroll
    for (int k = 0; k < 32; ++k) t32[k] = fmaxf(acc[k], acc[k + 32]);
    #pragma unroll
    for (int k = 0; k < 16; ++k) t32[k] = fmaxf(t32[k], t32[k + 16]);
    #pragma unroll
    for (int k = 0; k < 8; ++k)  t32[k] = fmaxf(t32[k], t32[k + 8]);
    #pragma unroll
    for (int k = 0; k < 4; ++k)  t32[k] = fmaxf(t32[k], t32[k + 4]);
    const float m01 = fmaxf(t32[0], t32[1]);
    const float m23 = fmaxf(t32[2], t32[3]);
    const float m = fmaxf(m01, m23);

    // sum of exp with 4 partial accumulators (shorter dep chains)
    float sp[4] = {0.0f, 0.0f, 0.0f, 0.0f};
    #pragma unroll
    for (int k = 0; k < KMIX; ++k)
        sp[k & 3] += __expf(acc[k] - m);
    const float s = (sp[0] + sp[1]) + (sp[2] + sp[3]);
    const float lse = m + __logf(s);

    // coalesced stores: per k, consecutive lanes hit consecutive n
    #pragma unroll
    for (int k = 0; k < KMIX; ++k)
        out[(size_t)k * NPTS + n] = acc[k] - lse;
}

extern "C" void kernel_launch(void* const* d_in, const int* in_sizes, int n_in,
                              void* d_out, int out_size, void* d_ws, size_t ws_size,
                              hipStream_t stream) {
    const float* inputs    = (const float*)d_in[0];  // (N, D)
    const float* mu        = (const float*)d_in[1];  // (K, D)
    const float* logvars   = (const float*)d_in[2];  // (K, D)
    const float* logpriors = (const float*)d_in[3];  // (K,)

    float* out = (float*)d_out;                       // (K, N)

    float* A  = (float*)d_ws;          // [K][D]
    float* B  = A + KMIX * DDIM;       // [K][D]
    float* Cc = B + KMIX * DDIM;       // [K]

    gmm_prep<<<KMIX, DDIM, 0, stream>>>(mu, logvars, logpriors, A, B, Cc);
    gmm_main<<<NPTS / 256, 256, 0, stream>>>(inputs, A, B, Cc, out);
}

// Round 4
// 151.914 us; speedup vs baseline: 2.0781x; 1.6867x over previous
//
#include <hip/hip_runtime.h>
#include <math.h>

#define NPTS 131072
#define DDIM 64
#define KMIX 64
#define LOG_2PI 1.8378770664093453f

#define KSPLIT 4              // waves per block, each owns KMIX/KSPLIT components
#define KT (KMIX / KSPLIT)    // 16 k per thread -> acc[16] stays in VGPRs

// ---------------------------------------------------------------------------
// Prep: 64 blocks (k) x 64 threads (d). Coefficients k-major:
//   A[k][d] = -0.5*exp(-lv),  B[k][d] = mu*exp(-lv)
//   C[k] = sum_d(-0.5*lv - 0.5*mu^2*exp(-lv)) - 0.5*D*log2pi + (lp[k]-LSE(lp))
// ---------------------------------------------------------------------------
__global__ void gmm_prep(const float* __restrict__ mu,
                         const float* __restrict__ lv,
                         const float* __restrict__ lp,
                         float* __restrict__ A,   // [KMIX][DDIM]
                         float* __restrict__ B,   // [KMIX][DDIM]
                         float* __restrict__ C)   // [KMIX]
{
    const int k = blockIdx.x;   // 0..63
    const int d = threadIdx.x;  // 0..63

    float x = lp[d];
    float m = x;
    #pragma unroll
    for (int off = 32; off > 0; off >>= 1)
        m = fmaxf(m, __shfl_xor(m, off, 64));
    float s = expf(x - m);
    #pragma unroll
    for (int off = 32; off > 0; off >>= 1)
        s += __shfl_xor(s, off, 64);
    const float lse_lp = m + logf(s);

    const float l  = lv[k * DDIM + d];
    const float ev = expf(-l);
    const float mv = mu[k * DDIM + d];
    A[k * DDIM + d] = -0.5f * ev;
    B[k * DDIM + d] = mv * ev;

    float c = -0.5f * l - 0.5f * mv * mv * ev;
    #pragma unroll
    for (int off = 32; off > 0; off >>= 1)
        c += __shfl_xor(c, off, 64);
    if (d == 0)
        C[k] = c + (lp[k] - lse_lp) - 0.5f * (float)DDIM * LOG_2PI;
}

// ---------------------------------------------------------------------------
// Main: block = 64 n x 4 waves. Wave kq (= tid>>6, forced scalar) owns
// k in [16*kq, 16*kq+16); thread = one n with acc[16] (guaranteed-resident
// register count). Coefficient addresses are wave-uniform -> scalar/broadcast
// loads, each amortized over 16 FMAs. All 4 waves stream the same 64 x-rows
// (L1 reuse). LSE over K = in-thread partial (m,s) over 16 k + 4-way combine
// through 2 KB LDS. Stores coalesced (lanes = consecutive n per k-row).
// ---------------------------------------------------------------------------
__global__ __launch_bounds__(256, 6)
void gmm_main(const float* __restrict__ xg,
              const float* __restrict__ A,
              const float* __restrict__ B,
              const float* __restrict__ C,
              float* __restrict__ out)
{
    __shared__ float sm[KSPLIT][64];
    __shared__ float ss[KSPLIT][64];

    const int nsub = threadIdx.x & 63;
    const int kq   = __builtin_amdgcn_readfirstlane(threadIdx.x >> 6);
    const int k0   = kq * KT;
    const int n    = blockIdx.x * 64 + nsub;
    const float* __restrict__ xr = xg + (size_t)n * DDIM;

    float acc[KT];
    #pragma unroll
    for (int kk = 0; kk < KT; ++kk) acc[kk] = 0.0f;

    #pragma unroll 1
    for (int dc = 0; dc < DDIM; dc += 8) {
        const float4 xa = *(const float4*)(xr + dc);
        const float4 xb = *(const float4*)(xr + dc + 4);
        const float xv0 = xa.x, xv1 = xa.y, xv2 = xa.z, xv3 = xa.w;
        const float xv4 = xb.x, xv5 = xb.y, xv6 = xb.z, xv7 = xb.w;
        const float q0 = xv0 * xv0, q1 = xv1 * xv1, q2 = xv2 * xv2, q3 = xv3 * xv3;
        const float q4 = xv4 * xv4, q5 = xv5 * xv5, q6 = xv6 * xv6, q7 = xv7 * xv7;

        #pragma unroll
        for (int kk = 0; kk < KT; ++kk) {
            const float* __restrict__ a = A + (k0 + kk) * DDIM + dc; // uniform
            const float* __restrict__ b = B + (k0 + kk) * DDIM + dc; // uniform
            float t = acc[kk];
            t = fmaf(q0, a[0], t); t = fmaf(xv0, b[0], t);
            t = fmaf(q1, a[1], t); t = fmaf(xv1, b[1], t);
            t = fmaf(q2, a[2], t); t = fmaf(xv2, b[2], t);
            t = fmaf(q3, a[3], t); t = fmaf(xv3, b[3], t);
            t = fmaf(q4, a[4], t); t = fmaf(xv4, b[4], t);
            t = fmaf(q5, a[5], t); t = fmaf(xv5, b[5], t);
            t = fmaf(q6, a[6], t); t = fmaf(xv6, b[6], t);
            t = fmaf(q7, a[7], t); t = fmaf(xv7, b[7], t);
            acc[kk] = t;
        }
    }

    // add per-k constants (uniform scalar loads)
    #pragma unroll
    for (int kk = 0; kk < KT; ++kk) acc[kk] += C[k0 + kk];

    // in-thread partial logsumexp over this wave's 16 k
    float t8[8];
    #pragma unroll
    for (int kk = 0; kk < 8; ++kk) t8[kk] = fmaxf(acc[kk], acc[kk + 8]);
    #pragma unroll
    for (int kk = 0; kk < 4; ++kk) t8[kk] = fmaxf(t8[kk], t8[kk + 4]);
    const float mp = fmaxf(fmaxf(t8[0], t8[1]), fmaxf(t8[2], t8[3]));

    float sp0 = 0.0f, sp1 = 0.0f, sp2 = 0.0f, sp3 = 0.0f;
    #pragma unroll
    for (int kk = 0; kk < KT; kk += 4) {
        sp0 += __expf(acc[kk + 0] - mp);
        sp1 += __expf(acc[kk + 1] - mp);
        sp2 += __expf(acc[kk + 2] - mp);
        sp3 += __expf(acc[kk + 3] - mp);
    }
    const float spart = (sp0 + sp1) + (sp2 + sp3);

    sm[kq][nsub] = mp;
    ss[kq][nsub] = spart;
    __syncthreads();

    // combine the 4 wave-partials for this n (every wave redundantly)
    const float m0 = sm[0][nsub], m1 = sm[1][nsub];
    const float m2 = sm[2][nsub], m3 = sm[3][nsub];
    const float mg = fmaxf(fmaxf(m0, m1), fmaxf(m2, m3));
    const float sg = ss[0][nsub] * __expf(m0 - mg)
                   + ss[1][nsub] * __expf(m1 - mg)
                   + ss[2][nsub] * __expf(m2 - mg)
                   + ss[3][nsub] * __expf(m3 - mg);
    const float lse = mg + __logf(sg);

    // coalesced stores: per k-row, lanes write consecutive n
    #pragma unroll
    for (int kk = 0; kk < KT; ++kk)
        out[(size_t)(k0 + kk) * NPTS + n] = acc[kk] - lse;
}

extern "C" void kernel_launch(void* const* d_in, const int* in_sizes, int n_in,
                              void* d_out, int out_size, void* d_ws, size_t ws_size,
                              hipStream_t stream) {
    const float* inputs    = (const float*)d_in[0];  // (N, D)
    const float* mu        = (const float*)d_in[1];  // (K, D)
    const float* logvars   = (const float*)d_in[2];  // (K, D)
    const float* logpriors = (const float*)d_in[3];  // (K,)

    float* out = (float*)d_out;                       // (K, N)

    float* A  = (float*)d_ws;          // [K][D]
    float* B  = A + KMIX * DDIM;       // [K][D]
    float* Cc = B + KMIX * DDIM;       // [K]

    gmm_prep<<<KMIX, DDIM, 0, stream>>>(mu, logvars, logpriors, A, B, Cc);
    gmm_main<<<NPTS / 64, 256, 0, stream>>>(inputs, A, B, Cc, out);
}

// Round 5
// 126.474 us; speedup vs baseline: 2.4962x; 1.2011x over previous
//
#include <hip/hip_runtime.h>
#include <math.h>

#define NPTS 131072
#define DDIM 64
#define KMIX 64
#define LOG_2PI 1.8378770664093453f

typedef __attribute__((ext_vector_type(8))) short short8;   // 8 bf16 (4 VGPRs)
typedef __attribute__((ext_vector_type(4))) float floatx4;  // 4 fp32 acc

// bf16 helpers (RNE)
static __device__ __forceinline__ unsigned short f2bf(float f) {
    unsigned int u = __float_as_uint(f);
    unsigned int r = (u + 0x7fffu + ((u >> 16) & 1u)) >> 16;
    return (unsigned short)r;
}
static __device__ __forceinline__ float bf2f(unsigned short h) {
    return __uint_as_float(((unsigned int)h) << 16);
}

// ---------------------------------------------------------------------------
// Prep 1: 64 blocks (k) x 64 threads (d).
//   Wf32[k][i]: i<64 -> A[k][i] = -0.5*exp(-lv); i>=64 -> B[k][i-64] = mu*exp(-lv)
//   C[k] = sum_d(-0.5*lv - 0.5*mu^2*exp(-lv)) - 0.5*D*log2pi + (lp[k]-LSE(lp))
// ---------------------------------------------------------------------------
__global__ void gmm_prep(const float* __restrict__ mu,
                         const float* __restrict__ lv,
                         const float* __restrict__ lp,
                         float* __restrict__ Wf32,   // [KMIX][128]
                         float* __restrict__ C)      // [KMIX]
{
    const int k = blockIdx.x;
    const int d = threadIdx.x;

    float x = lp[d];
    float m = x;
    #pragma unroll
    for (int off = 32; off > 0; off >>= 1)
        m = fmaxf(m, __shfl_xor(m, off, 64));
    float s = expf(x - m);
    #pragma unroll
    for (int off = 32; off > 0; off >>= 1)
        s += __shfl_xor(s, off, 64);
    const float lse_lp = m + logf(s);

    const float l  = lv[k * DDIM + d];
    const float ev = expf(-l);
    const float mv = mu[k * DDIM + d];
    Wf32[k * 128 + d]      = -0.5f * ev;
    Wf32[k * 128 + 64 + d] = mv * ev;

    float c = -0.5f * l - 0.5f * mv * mv * ev;
    #pragma unroll
    for (int off = 32; off > 0; off >>= 1)
        c += __shfl_xor(c, off, 64);
    if (d == 0)
        C[k] = c + (lp[k] - lse_lp) - 0.5f * (float)DDIM * LOG_2PI;
}

// ---------------------------------------------------------------------------
// Prep 2: pack W into MFMA A-fragment order, hi/lo bf16 split.
// Fragment (ktile t, itile u): lane l holds W[t*16 + (l&15)][u*32 + (l>>4)*8 + j].
// Pack offset: ((t*4+u)*64 + lane)*8 + j   (so a frag load = lane-linear 16 B).
// ---------------------------------------------------------------------------
__global__ void gmm_pack(const float* __restrict__ Wf32,
                         unsigned short* __restrict__ WhPack,
                         unsigned short* __restrict__ WlPack)
{
    const int b    = blockIdx.x;          // t*4 + u
    const int lane = threadIdx.x;         // 0..63
    const int krow = (b >> 2) * 16 + (lane & 15);
    const int ibase = (b & 3) * 32 + (lane >> 4) * 8;
    #pragma unroll
    for (int j = 0; j < 8; ++j) {
        const float f = Wf32[krow * 128 + ibase + j];
        const unsigned short h = f2bf(f);
        WhPack[(b * 64 + lane) * 8 + j] = h;
        WlPack[(b * 64 + lane) * 8 + j] = f2bf(f - bf2f(h));
    }
}

// ---------------------------------------------------------------------------
// Main: wave = 16 examples per unit, 2 units. Lane l computes, in registers,
// the B-fragments F[i = u*32+(l>>4)*8+j][n = n0+(l&15)] (features = [x^2; x],
// hi/lo bf16 split) -- no LDS for F. A-fragments: Wh hoisted in 64 VGPRs,
// Wl read per unit from LDS (lane-linear ds_read_b128). 3 MFMA passes:
//   acc += Wh*Fh + Wh*Fl + Wl*Fh   (dropped Wl*Fl term ~2^-18 rel)
// C/D layout col=lane&15,row=(lane>>4)*4+reg -> per-lane 16 k-values; LSE =
// in-thread 16-max/sum + shfl_xor(16,32). Stores: 4x64B segments per instr.
// ---------------------------------------------------------------------------
__global__ __launch_bounds__(256, 3)
void gmm_main(const float* __restrict__ xg,
              const unsigned short* __restrict__ WhPack,
              const unsigned short* __restrict__ WlPack,
              const float* __restrict__ C,
              float* __restrict__ out)
{
    __shared__ unsigned short WlLds[16 * 64 * 8];   // 16 KB

    // cooperative Wl load (once per block)
    #pragma unroll
    for (int it = 0; it < 4; ++it) {
        const int idx = it * 256 + threadIdx.x;
        ((uint4*)WlLds)[idx] = ((const uint4*)WlPack)[idx];
    }
    __syncthreads();

    const int lane = threadIdx.x & 63;
    const int wid  = __builtin_amdgcn_readfirstlane(threadIdx.x >> 6);
    const int g    = lane >> 4;      // quad
    const int nn   = lane & 15;      // column within tile

    // hoisted Wh fragments (16 x 4 VGPR = 64 VGPR)
    short8 wh[4][4];
    #pragma unroll
    for (int t = 0; t < 4; ++t)
        #pragma unroll
        for (int u = 0; u < 4; ++u)
            wh[t][u] = *(const short8*)(WhPack + ((t * 4 + u) * 64 + lane) * 8);

    // hoisted C values for this lane's 16 k's
    floatx4 cw[4];
    #pragma unroll
    for (int t = 0; t < 4; ++t)
        cw[t] = *(const floatx4*)(C + t * 16 + g * 4);

    const int wgid = blockIdx.x * 4 + wid;

    #pragma unroll 1
    for (int unit = 0; unit < 2; ++unit) {
        const int n0 = wgid * 32 + unit * 16;

        // lane's x chunks: row n0+nn, d in [g*8, g*8+8) and [32+g*8, 32+g*8+8)
        const float* __restrict__ xr = xg + (size_t)(n0 + nn) * DDIM + g * 8;
        const float4 p0 = *(const float4*)(xr);
        const float4 p1 = *(const float4*)(xr + 4);
        const float4 p2 = *(const float4*)(xr + 32);
        const float4 p3 = *(const float4*)(xr + 36);
        const float ca[8] = {p0.x, p0.y, p0.z, p0.w, p1.x, p1.y, p1.z, p1.w};
        const float cb[8] = {p2.x, p2.y, p2.z, p2.w, p3.x, p3.y, p3.z, p3.w};

        // build B-fragments in registers: u=0: x^2 (chunk A), u=1: x^2 (chunk B),
        // u=2: x (chunk A), u=3: x (chunk B); hi + lo splits.
        short8 bh[4], bl[4];
        #pragma unroll
        for (int j = 0; j < 8; ++j) {
            const float qa = ca[j] * ca[j];
            const float qb = cb[j] * cb[j];
            unsigned short h;
            h = f2bf(qa);    bh[0][j] = (short)h; bl[0][j] = (short)f2bf(qa    - bf2f(h));
            h = f2bf(qb);    bh[1][j] = (short)h; bl[1][j] = (short)f2bf(qb    - bf2f(h));
            h = f2bf(ca[j]); bh[2][j] = (short)h; bl[2][j] = (short)f2bf(ca[j] - bf2f(h));
            h = f2bf(cb[j]); bh[3][j] = (short)h; bl[3][j] = (short)f2bf(cb[j] - bf2f(h));
        }

        floatx4 acc[4];
        #pragma unroll
        for (int t = 0; t < 4; ++t) acc[t] = (floatx4){0.f, 0.f, 0.f, 0.f};

        #pragma unroll
        for (int u = 0; u < 4; ++u) {
            #pragma unroll
            for (int t = 0; t < 4; ++t) {
                const short8 wlf = *(const short8*)(WlLds + ((t * 4 + u) * 64 + lane) * 8);
                acc[t] = __builtin_amdgcn_mfma_f32_16x16x32_bf16(wh[t][u], bh[u], acc[t], 0, 0, 0);
                acc[t] = __builtin_amdgcn_mfma_f32_16x16x32_bf16(wh[t][u], bl[u], acc[t], 0, 0, 0);
                acc[t] = __builtin_amdgcn_mfma_f32_16x16x32_bf16(wlf,      bh[u], acc[t], 0, 0, 0);
            }
        }

        // epilogue: add C, LSE over the 64 k's of column nn
        float w[16];
        #pragma unroll
        for (int t = 0; t < 4; ++t)
            #pragma unroll
            for (int r = 0; r < 4; ++r)
                w[t * 4 + r] = acc[t][r] + cw[t][r];

        float t8[8];
        #pragma unroll
        for (int i = 0; i < 8; ++i) t8[i] = fmaxf(w[i], w[i + 8]);
        #pragma unroll
        for (int i = 0; i < 4; ++i) t8[i] = fmaxf(t8[i], t8[i + 4]);
        float m = fmaxf(fmaxf(t8[0], t8[1]), fmaxf(t8[2], t8[3]));
        m = fmaxf(m, __shfl_xor(m, 16, 64));
        m = fmaxf(m, __shfl_xor(m, 32, 64));

        float s0 = 0.f, s1 = 0.f, s2 = 0.f, s3 = 0.f;
        #pragma unroll
        for (int i = 0; i < 16; i += 4) {
            s0 += __expf(w[i + 0] - m);
            s1 += __expf(w[i + 1] - m);
            s2 += __expf(w[i + 2] - m);
            s3 += __expf(w[i + 3] - m);
        }
        float s = (s0 + s1) + (s2 + s3);
        s += __shfl_xor(s, 16, 64);
        s += __shfl_xor(s, 32, 64);
        const float lse = m + __logf(s);

        const size_t nidx = (size_t)n0 + nn;
        #pragma unroll
        for (int t = 0; t < 4; ++t)
            #pragma unroll
            for (int r = 0; r < 4; ++r)
                out[(size_t)(t * 16 + g * 4 + r) * NPTS + nidx] = w[t * 4 + r] - lse;
    }
}

extern "C" void kernel_launch(void* const* d_in, const int* in_sizes, int n_in,
                              void* d_out, int out_size, void* d_ws, size_t ws_size,
                              hipStream_t stream) {
    const float* inputs    = (const float*)d_in[0];  // (N, D)
    const float* mu        = (const float*)d_in[1];  // (K, D)
    const float* logvars   = (const float*)d_in[2];  // (K, D)
    const float* logpriors = (const float*)d_in[3];  // (K,)

    float* out = (float*)d_out;                       // (K, N)

    // ws layout: WhPack 16 KB | WlPack 16 KB | Wf32 32 KB | C 256 B
    unsigned short* WhPack = (unsigned short*)d_ws;
    unsigned short* WlPack = WhPack + KMIX * 128;
    float* Wf32 = (float*)(WlPack + KMIX * 128);
    float* Cc   = Wf32 + KMIX * 128;

    gmm_prep<<<KMIX, DDIM, 0, stream>>>(mu, logvars, logpriors, Wf32, Cc);
    gmm_pack<<<16, 64, 0, stream>>>(Wf32, WhPack, WlPack);
    gmm_main<<<NPTS / 128, 256, 0, stream>>>(inputs, WhPack, WlPack, Cc, out);
}

// Round 6
// 96.242 us; speedup vs baseline: 3.2803x; 1.3141x over previous
//
#include <hip/hip_runtime.h>
#include <math.h>

#define NPTS 131072
#define DDIM 64
#define KMIX 64
#define LOG_2PI 1.8378770664093453f

typedef __attribute__((ext_vector_type(8))) short short8;   // 8 bf16 (4 VGPRs)
typedef __attribute__((ext_vector_type(4))) float floatx4;  // 4 fp32 acc

// bf16 helpers (RNE)
static __device__ __forceinline__ unsigned short f2bf(float f) {
    unsigned int u = __float_as_uint(f);
    unsigned int r = (u + 0x7fffu + ((u >> 16) & 1u)) >> 16;
    return (unsigned short)r;
}

// ---------------------------------------------------------------------------
// Prep 1: 64 blocks (k) x 64 threads (d).
//   Wf32[k][i]: i<64 -> A[k][i] = -0.5*exp(-lv); i>=64 -> B[k][i-64] = mu*exp(-lv)
//   C[k] = sum_d(-0.5*lv - 0.5*mu^2*exp(-lv)) - 0.5*D*log2pi + (lp[k]-LSE(lp))
// ---------------------------------------------------------------------------
__global__ void gmm_prep(const float* __restrict__ mu,
                         const float* __restrict__ lv,
                         const float* __restrict__ lp,
                         float* __restrict__ Wf32,   // [KMIX][128]
                         float* __restrict__ C)      // [KMIX]
{
    const int k = blockIdx.x;
    const int d = threadIdx.x;

    float x = lp[d];
    float m = x;
    #pragma unroll
    for (int off = 32; off > 0; off >>= 1)
        m = fmaxf(m, __shfl_xor(m, off, 64));
    float s = expf(x - m);
    #pragma unroll
    for (int off = 32; off > 0; off >>= 1)
        s += __shfl_xor(s, off, 64);
    const float lse_lp = m + logf(s);

    const float l  = lv[k * DDIM + d];
    const float ev = expf(-l);
    const float mv = mu[k * DDIM + d];
    Wf32[k * 128 + d]      = -0.5f * ev;
    Wf32[k * 128 + 64 + d] = mv * ev;

    float c = -0.5f * l - 0.5f * mv * mv * ev;
    #pragma unroll
    for (int off = 32; off > 0; off >>= 1)
        c += __shfl_xor(c, off, 64);
    if (d == 0)
        C[k] = c + (lp[k] - lse_lp) - 0.5f * (float)DDIM * LOG_2PI;
}

// ---------------------------------------------------------------------------
// Prep 2: pack W (bf16) into MFMA A-fragment order.
// Fragment (ktile t, itile u): lane l holds W[t*16 + (l&15)][u*32 + (l>>4)*8 + j]
// at offset ((t*4+u)*64 + lane)*8 + j  (frag load = lane-linear 16 B).
// ---------------------------------------------------------------------------
__global__ void gmm_pack(const float* __restrict__ Wf32,
                         unsigned short* __restrict__ WhPack)
{
    const int b    = blockIdx.x;          // t*4 + u
    const int lane = threadIdx.x;         // 0..63
    const int krow = (b >> 2) * 16 + (lane & 15);
    const int ibase = (b & 3) * 32 + (lane >> 4) * 8;
    #pragma unroll
    for (int j = 0; j < 8; ++j)
        WhPack[(b * 64 + lane) * 8 + j] = f2bf(Wf32[krow * 128 + ibase + j]);
}

// ---------------------------------------------------------------------------
// Main: wave = 16 examples (one MFMA column tile); block = 4 waves = 64 n.
// Lane l builds B-fragments F[i][n] in registers from its x-row (no LDS on
// the input path): F = [x^2 (d 0..63); x (d 0..63)], bf16. A-fragments (Wh)
// hoisted in 64 VGPRs. 16 MFMA per wave. LSE over 64 k = in-thread 16-value
// reduce + shfl_xor(16,32). Epilogue: block O-tile [64k][68] in LDS, then
// linear stores -- each instruction covers 256 B contiguous per k-row
// (4 full 128 B lines) to kill the R5 write amplification.
// ---------------------------------------------------------------------------
__global__ __launch_bounds__(256, 4)
void gmm_main(const float* __restrict__ xg,
              const unsigned short* __restrict__ WhPack,
              const float* __restrict__ C,
              float* __restrict__ out)
{
    __shared__ float O[KMIX * 68];   // 17.4 KB, padded row stride 68

    const int lane = threadIdx.x & 63;
    const int wid  = __builtin_amdgcn_readfirstlane(threadIdx.x >> 6);
    const int g    = lane >> 4;      // quad
    const int nn   = lane & 15;      // column within 16-wide tile

    const int bn0 = blockIdx.x * 64;            // block's n base
    const int n   = bn0 + wid * 16 + nn;        // this lane's example column

    // x loads first (longest latency): row n, d in [g*8,g*8+8) and [32+g*8,..)
    const float* __restrict__ xr = xg + (size_t)n * DDIM + g * 8;
    const float4 p0 = *(const float4*)(xr);
    const float4 p1 = *(const float4*)(xr + 4);
    const float4 p2 = *(const float4*)(xr + 32);
    const float4 p3 = *(const float4*)(xr + 36);

    // hoisted Wh fragments (16 x 4 VGPR = 64 VGPR), L1/L2-hot
    short8 wh[4][4];
    #pragma unroll
    for (int t = 0; t < 4; ++t)
        #pragma unroll
        for (int u = 0; u < 4; ++u)
            wh[t][u] = *(const short8*)(WhPack + ((t * 4 + u) * 64 + lane) * 8);

    // per-lane C values: rows t*16 + g*4 + r
    floatx4 cw[4];
    #pragma unroll
    for (int t = 0; t < 4; ++t)
        cw[t] = *(const floatx4*)(C + t * 16 + g * 4);

    const float ca[8] = {p0.x, p0.y, p0.z, p0.w, p1.x, p1.y, p1.z, p1.w};
    const float cb[8] = {p2.x, p2.y, p2.z, p2.w, p3.x, p3.y, p3.z, p3.w};

    // B-fragments in registers: u=0: x^2 (d<32), u=1: x^2 (d>=32),
    //                           u=2: x   (d<32), u=3: x   (d>=32)
    short8 bh[4];
    #pragma unroll
    for (int j = 0; j < 8; ++j) {
        bh[0][j] = (short)f2bf(ca[j] * ca[j]);
        bh[1][j] = (short)f2bf(cb[j] * cb[j]);
        bh[2][j] = (short)f2bf(ca[j]);
        bh[3][j] = (short)f2bf(cb[j]);
    }

    floatx4 acc[4];
    #pragma unroll
    for (int t = 0; t < 4; ++t) acc[t] = (floatx4){0.f, 0.f, 0.f, 0.f};

    #pragma unroll
    for (int u = 0; u < 4; ++u)
        #pragma unroll
        for (int t = 0; t < 4; ++t)
            acc[t] = __builtin_amdgcn_mfma_f32_16x16x32_bf16(wh[t][u], bh[u], acc[t], 0, 0, 0);

    // add C (reuse acc as w), then LSE over the 64 k's of column n
    #pragma unroll
    for (int t = 0; t < 4; ++t)
        #pragma unroll
        for (int r = 0; r < 4; ++r)
            acc[t][r] += cw[t][r];

    float t8[8];
    #pragma unroll
    for (int i = 0; i < 8; ++i)
        t8[i] = fmaxf(acc[i >> 2][i & 3], acc[2 + (i >> 2)][i & 3]);
    #pragma unroll
    for (int i = 0; i < 4; ++i) t8[i] = fmaxf(t8[i], t8[i + 4]);
    float m = fmaxf(fmaxf(t8[0], t8[1]), fmaxf(t8[2], t8[3]));
    m = fmaxf(m, __shfl_xor(m, 16, 64));
    m = fmaxf(m, __shfl_xor(m, 32, 64));

    float s0 = 0.f, s1 = 0.f, s2 = 0.f, s3 = 0.f;
    #pragma unroll
    for (int t = 0; t < 4; ++t) {
        s0 += __expf(acc[t][0] - m);
        s1 += __expf(acc[t][1] - m);
        s2 += __expf(acc[t][2] - m);
        s3 += __expf(acc[t][3] - m);
    }
    float s = (s0 + s1) + (s2 + s3);
    s += __shfl_xor(s, 16, 64);
    s += __shfl_xor(s, 32, 64);
    const float lse = m + __logf(s);

    // stage into block O-tile: row = t*16+g*4+r, col = wid*16+nn
    // (banks: quads 2-way aliased -> free)
    #pragma unroll
    for (int t = 0; t < 4; ++t)
        #pragma unroll
        for (int r = 0; r < 4; ++r)
            O[(t * 16 + g * 4 + r) * 68 + wid * 16 + nn] = acc[t][r] - lse;

    __syncthreads();

    // linear store: per instruction, 4 k-rows x 256 B contiguous (full lines)
    #pragma unroll
    for (int rr = 0; rr < 4; ++rr) {
        const int row = rr * 16 + (threadIdx.x >> 4);
        const int c4  = (threadIdx.x & 15) * 4;
        const float4 v = *(const float4*)&O[row * 68 + c4];
        *(float4*)&out[(size_t)row * NPTS + bn0 + c4] = v;
    }
}

extern "C" void kernel_launch(void* const* d_in, const int* in_sizes, int n_in,
                              void* d_out, int out_size, void* d_ws, size_t ws_size,
                              hipStream_t stream) {
    const float* inputs    = (const float*)d_in[0];  // (N, D)
    const float* mu        = (const float*)d_in[1];  // (K, D)
    const float* logvars   = (const float*)d_in[2];  // (K, D)
    const float* logpriors = (const float*)d_in[3];  // (K,)

    float* out = (float*)d_out;                       // (K, N)

    // ws layout: WhPack 16 KB | Wf32 32 KB | C 256 B
    unsigned short* WhPack = (unsigned short*)d_ws;
    float* Wf32 = (float*)(WhPack + KMIX * 128);
    float* Cc   = Wf32 + KMIX * 128;

    gmm_prep<<<KMIX, DDIM, 0, stream>>>(mu, logvars, logpriors, Wf32, Cc);
    gmm_pack<<<16, 64, 0, stream>>>(Wf32, WhPack);
    gmm_main<<<NPTS / 64, 256, 0, stream>>>(inputs, WhPack, Cc, out);
}